// Round 7
// baseline (203.035 us; speedup 1.0000x reference)
//
#include <hip/hip_runtime.h>
#include <hip/hip_bf16.h>
#include <cstdint>
#include <cstddef>

typedef __bf16 bf16_t;
typedef __bf16 bf16x4 __attribute__((ext_vector_type(4)));
typedef __bf16 bf16x8 __attribute__((ext_vector_type(8)));
typedef float  f32x4  __attribute__((ext_vector_type(4)));
typedef float  f32x16 __attribute__((ext_vector_type(16)));
typedef unsigned int u32;
typedef unsigned int u32x4 __attribute__((ext_vector_type(4)));

#define DIM_   1024
#define HEADS_ 16
#define HD_    64
#define BB_    2
#define NN_    2048
#define MTOT   (BB_*NN_)
static constexpr float SCALE_ = 0.03125f;              // 1/sqrt(1024)
static constexpr float EXPC_  = 0.045084220027780106f; // SCALE * log2(e), folded into q-proj

// ---------------------------------------------------------------------------
// fp32 -> bf16 bulk converts
// ---------------------------------------------------------------------------
__global__ __launch_bounds__(256) void cvt_bf16(
    const float* __restrict__ in, bf16_t* __restrict__ out)
{
    const size_t i = ((size_t)blockIdx.x * 256 + threadIdx.x) * 8;
    f32x4 a = *(const f32x4*)(in + i);
    f32x4 b = *(const f32x4*)(in + i + 4);
    bf16x8 o;
    o[0] = (bf16_t)a.x; o[1] = (bf16_t)a.y; o[2] = (bf16_t)a.z; o[3] = (bf16_t)a.w;
    o[4] = (bf16_t)b.x; o[5] = (bf16_t)b.y; o[6] = (bf16_t)b.z; o[7] = (bf16_t)b.w;
    *(bf16x8*)(out + i) = o;
}

__global__ __launch_bounds__(256) void cvt_w4(
    const float* __restrict__ W0, const float* __restrict__ W1,
    const float* __restrict__ W2, const float* __restrict__ W3,
    bf16_t* __restrict__ o0, bf16_t* __restrict__ o1,
    bf16_t* __restrict__ o2, bf16_t* __restrict__ o3)
{
    const int bid = blockIdx.x;
    const int w   = bid >> 9;                 // 0..3
    const float* src = (w == 0) ? W0 : (w == 1) ? W1 : (w == 2) ? W2 : W3;
    bf16_t*      dst = (w == 0) ? o0 : (w == 1) ? o1 : (w == 2) ? o2 : o3;
    const size_t i = ((size_t)(bid & 511) * 256 + threadIdx.x) * 8;
    f32x4 a = *(const f32x4*)(src + i);
    f32x4 b = *(const f32x4*)(src + i + 4);
    bf16x8 o;
    o[0] = (bf16_t)a.x; o[1] = (bf16_t)a.y; o[2] = (bf16_t)a.z; o[3] = (bf16_t)a.w;
    o[4] = (bf16_t)b.x; o[5] = (bf16_t)b.y; o[6] = (bf16_t)b.z; o[7] = (bf16_t)b.w;
    *(bf16x8*)(dst + i) = o;
}

// ---------------------------------------------------------------------------
// gemm_bb: C = (A(bf16) @ Wb(bf16)^T + bias) * osc.  m97 structure.
// ---------------------------------------------------------------------------
__device__ __forceinline__ void gld16(const bf16_t* g, bf16_t* l) {
    __builtin_amdgcn_global_load_lds(
        (const __attribute__((address_space(1))) unsigned int*)g,
        (__attribute__((address_space(3))) unsigned int*)l, 16, 0, 0);
}

template<bool CBF>
__global__ __launch_bounds__(256) void gemm_bb(
    const bf16_t* __restrict__ A,
    const bf16_t* __restrict__ W0, const bf16_t* __restrict__ W1, const bf16_t* __restrict__ W2,
    const float* __restrict__ B0, const float* __restrict__ B1, const float* __restrict__ B2,
    void* __restrict__ C0, void* __restrict__ C1, void* __restrict__ C2,
    float s0, float s1, float s2,
    int M, int N, int K)
{
    const bf16_t* Wt  = (blockIdx.z == 0) ? W0 : (blockIdx.z == 1 ? W1 : W2);
    const float* bias = (blockIdx.z == 0) ? B0 : (blockIdx.z == 1 ? B1 : B2);
    void*        Cp   = (blockIdx.z == 0) ? C0 : (blockIdx.z == 1 ? C1 : C2);
    const float  osc  = (blockIdx.z == 0) ? s0 : (blockIdx.z == 1 ? s1 : s2);

    __shared__ __align__(16) bf16_t As[128 * 64];
    __shared__ __align__(16) bf16_t Bs[128 * 64];

    const int tid  = threadIdx.x;
    const int lane = tid & 63;
    const int wave = tid >> 6;
    const int wr   = wave >> 1;
    const int wc   = wave & 1;
    const int bm   = blockIdx.y, bn = blockIdx.x;

    const int l15 = lane & 15;
    const int g   = lane >> 4;

    const int grow = lane >> 3;
    const int gcol = (lane & 7) * 8;

    f32x4 acc[4][4];
    #pragma unroll
    for (int i = 0; i < 4; i++)
        #pragma unroll
        for (int j = 0; j < 4; j++)
            acc[i][j] = (f32x4){0.f, 0.f, 0.f, 0.f};

    for (int kb = 0; kb < K; kb += 64) {
        __syncthreads();
        #pragma unroll
        for (int i = 0; i < 4; i++) {
            const int r0 = i * 32 + wave * 8;
            gld16(A  + (size_t)(bm * 128 + r0 + grow) * K + kb + gcol, As + r0 * 64);
            gld16(Wt + (size_t)(bn * 128 + r0 + grow) * K + kb + gcol, Bs + r0 * 64);
        }
        __syncthreads();

        #pragma unroll
        for (int kk = 0; kk < 2; kk++) {
            bf16x8 af[4], bfr[4];
            #pragma unroll
            for (int i = 0; i < 4; i++) {
                af[i]  = *(const bf16x8*)&As[(wr * 64 + i * 16 + l15) * 64 + kk * 32 + g * 8];
                bfr[i] = *(const bf16x8*)&Bs[(wc * 64 + i * 16 + l15) * 64 + kk * 32 + g * 8];
            }
            #pragma unroll
            for (int i = 0; i < 4; i++)
                #pragma unroll
                for (int j = 0; j < 4; j++)
                    acc[i][j] = __builtin_amdgcn_mfma_f32_16x16x32_bf16(af[i], bfr[j], acc[i][j], 0, 0, 0);
        }
    }

    const int r4 = (lane >> 4) * 4;
    #pragma unroll
    for (int j = 0; j < 4; j++) {
        const int gc = bn * 128 + wc * 64 + j * 16 + l15;
        const float bv = bias[gc];
        #pragma unroll
        for (int i = 0; i < 4; i++) {
            #pragma unroll
            for (int r = 0; r < 4; r++) {
                const int gr = bm * 128 + wr * 64 + i * 16 + r4 + r;
                const float val = (acc[i][j][r] + bv) * osc;
                if (CBF) ((bf16_t*)Cp)[(size_t)gr * N + gc] = (bf16_t)val;
                else     ((float*)Cp)[(size_t)gr * N + gc]  = val;
            }
        }
    }
}

// ---------------------------------------------------------------------------
// Per-head transpose: V[b][m][h*64+d] -> Vt[(b*16+h)*64 + d][m]
// ---------------------------------------------------------------------------
__global__ __launch_bounds__(256) void transpose_v(
    const bf16_t* __restrict__ V, bf16_t* __restrict__ Vt)
{
    __shared__ __align__(16) bf16_t Ts[64 * 72];
    const int tid = threadIdx.x;
    const int mt  = blockIdx.x;
    const int bh  = blockIdx.y;
    const int b   = bh >> 4, h = bh & 15;
    const int m0  = mt * 64;
    const int r   = tid >> 2;
    const int c   = (tid & 3) * 16;

    const bf16x8* s = (const bf16x8*)(V + ((size_t)(b * NN_ + m0 + r)) * DIM_ + h * HD_ + c);
    *(bf16x8*)(Ts + r * 72 + c)     = s[0];
    *(bf16x8*)(Ts + r * 72 + c + 8) = s[1];
    __syncthreads();

    bf16x8 o0, o1;
    #pragma unroll
    for (int i = 0; i < 8; i++) o0[i] = Ts[(c + i) * 72 + r];
    #pragma unroll
    for (int i = 0; i < 8; i++) o1[i] = Ts[(c + 8 + i) * 72 + r];
    bf16_t* dst = Vt + ((size_t)bh * HD_ + r) * NN_ + m0 + c;
    *(bf16x8*)dst       = o0;
    *(bf16x8*)(dst + 8) = o1;
}

// ---------------------------------------------------------------------------
// MFMA attention v5: m-split occupancy version.
// 1024 blocks x 4 waves; block owns 64 n-rows; wave pair (w&1 = n-half is
// NOT split; w>>1 = m-half IS split): waves 0,1 -> m[0,64), waves 2,3 ->
// m[64,128) of each 128-m tile. Partial O/L merged via LDS at the end.
// Single-buffer K/V (35.8KB LDS), issue-early/commit-late staging.
// ---------------------------------------------------------------------------
__device__ __forceinline__ u32 cvtpk_bf16(float lo, float hi) {
    u32 d;
    asm volatile("v_cvt_pk_bf16_f32 %0, %1, %2" : "=v"(d) : "v"(lo), "v"(hi));
    return d;
}

__global__ __launch_bounds__(256, 4) void attn_mfma5(
    const bf16_t* __restrict__ Qa,   // kb (attention-query rows n)
    const bf16_t* __restrict__ Ka,   // qb (attention-key rows m, pre-scaled by EXPC_)
    const bf16_t* __restrict__ Vtg,  // V^T per head [bh][d][m]
    bf16_t* __restrict__ O)
{
    __shared__ __align__(16) bf16_t Kt[128 * 72];
    __shared__ __align__(16) bf16_t Vt[64 * 136];

    const int tid  = threadIdx.x;
    const int lane = tid & 63;
    const int w    = tid >> 6;
    const int l31  = lane & 31;
    const int h5   = lane >> 5;

    const int mo = (w >> 1) * 64;    // this wave's m-half within each tile
    const int nw = (w & 1) * 32;     // this wave's n-offset within block

    // XCD-chunked swizzle: 1024 blocks, 128 consecutive ids per XCD
    const int wg = blockIdx.x;
    const int id = (wg & 7) * 128 + (wg >> 3);
    const int bh = id >> 5;          // 0..31
    const int nt = id & 31;          // 0..31
    const int b  = bh >> 4, h = bh & 15;
    const int n0 = nt * 64;

    const size_t base = (size_t)b * NN_ * DIM_ + h * HD_;

    // Q-fragments (B-operand, n = n0 + nw + l31) straight from global
    const bf16_t* qrow = Qa + base + (size_t)(n0 + nw + l31) * DIM_ + h5 * 8;
    bf16x8 qf[4];
    #pragma unroll
    for (int ks = 0; ks < 4; ks++)
        qf[ks] = *(const bf16x8*)(qrow + ks * 16);

    u32x4 onesw;
    onesw.x = 0x3F803F80u; onesw.y = 0x3F803F80u; onesw.z = 0x3F803F80u; onesw.w = 0x3F803F80u;
    const bf16x8 onesf = __builtin_bit_cast(bf16x8, onesw);

    f32x16 oa0 = {}, oa1 = {}, oL = {};

    const bf16_t* vrow   = Vtg + (size_t)bh * HD_ * NN_;
    const bf16_t* kgbase = Ka + base;
    const int kr  = tid >> 2;          // 0..63
    const int kc  = (tid & 3) * 16;    // K d-col: 0/16/32/48
    const int vcm = (tid & 3) * 32;    // V m-col base: 0/32/64/96

    bf16x8 kA0, kA1, kB0, kB1, vA0, vA1, vA2, vA3;

    #define ISSUE(m0)                                                                 \
        {                                                                             \
            const bf16x8* kp0 = (const bf16x8*)(kgbase + (size_t)((m0) + kr) * DIM_ + kc);       \
            kA0 = kp0[0]; kA1 = kp0[1];                                               \
            const bf16x8* kp1 = (const bf16x8*)(kgbase + (size_t)((m0) + 64 + kr) * DIM_ + kc);  \
            kB0 = kp1[0]; kB1 = kp1[1];                                               \
            const bf16x8* vp = (const bf16x8*)(vrow + (size_t)kr * NN_ + (m0) + vcm); \
            vA0 = vp[0]; vA1 = vp[1]; vA2 = vp[2]; vA3 = vp[3];                       \
        }
    #define COMMIT()                                                                  \
        {                                                                             \
            *(bf16x8*)(Kt + kr * 72 + kc)            = kA0;                           \
            *(bf16x8*)(Kt + kr * 72 + kc + 8)        = kA1;                           \
            *(bf16x8*)(Kt + (64 + kr) * 72 + kc)     = kB0;                           \
            *(bf16x8*)(Kt + (64 + kr) * 72 + kc + 8) = kB1;                           \
            bf16_t* vd = Vt + kr * 136 + vcm;                                         \
            *(bf16x8*)(vd)      = vA0; *(bf16x8*)(vd + 8)  = vA1;                     \
            *(bf16x8*)(vd + 16) = vA2; *(bf16x8*)(vd + 24) = vA3;                     \
        }

    ISSUE(0);
    COMMIT();
    __syncthreads();

    for (int mt = 0; mt < NN_ / 128; mt++) {
        if (mt < NN_ / 128 - 1) ISSUE((mt + 1) * 128);

        // S^T for this wave's m-half: lane holds 32 P-vals for n = nw + l31
        f32x16 sa0 = {}, sa1 = {};
        __builtin_amdgcn_s_setprio(1);
        #pragma unroll
        for (int ks = 0; ks < 4; ks++) {
            bf16x8 kf0 = *(const bf16x8*)&Kt[(mo + l31) * 72 + ks * 16 + h5 * 8];
            bf16x8 kf1 = *(const bf16x8*)&Kt[(mo + 32 + l31) * 72 + ks * 16 + h5 * 8];
            sa0 = __builtin_amdgcn_mfma_f32_32x32x16_bf16(kf0, qf[ks], sa0, 0, 0, 0);
            sa1 = __builtin_amdgcn_mfma_f32_32x32x16_bf16(kf1, qf[ks], sa1, 0, 0, 0);
        }
        __builtin_amdgcn_s_setprio(0);

        // P = exp2(S^T)  (scale pre-folded into Ka)
        float p0[16], p1[16];
        #pragma unroll
        for (int r = 0; r < 16; r++) { p0[r] = exp2f(sa0[r]); p1[r] = exp2f(sa1[r]); }

        // PV A-fragments in-register: 16 cvt_pk + 8 permlane32_swap
        bf16x8 pf[4];
        #pragma unroll
        for (int mb = 0; mb < 4; mb++) {
            const float* pp = (mb & 2) ? p1 : p0;
            const int rb = (mb & 1) * 8;
            u32 x0 = cvtpk_bf16(pp[rb + 0], pp[rb + 1]);
            u32 x1 = cvtpk_bf16(pp[rb + 2], pp[rb + 3]);
            u32 y0 = cvtpk_bf16(pp[rb + 4], pp[rb + 5]);
            u32 y1 = cvtpk_bf16(pp[rb + 6], pp[rb + 7]);
            asm volatile("v_permlane32_swap_b32 %0, %1" : "+v"(x0), "+v"(y0));
            asm volatile("v_permlane32_swap_b32 %0, %1" : "+v"(x1), "+v"(y1));
            u32x4 t; t.x = x0; t.y = x1; t.z = y0; t.w = y1;
            pf[mb] = __builtin_bit_cast(bf16x8, t);
        }

        // O += P·V ; L += P·1   (this wave's m-half only)
        __builtin_amdgcn_s_setprio(1);
        #pragma unroll
        for (int ms = 0; ms < 4; ms++) {
            bf16x8 vf0 = *(const bf16x8*)&Vt[l31 * 136 + mo + ms * 16 + h5 * 8];
            bf16x8 vf1 = *(const bf16x8*)&Vt[(32 + l31) * 136 + mo + ms * 16 + h5 * 8];
            oa0 = __builtin_amdgcn_mfma_f32_32x32x16_bf16(pf[ms], vf0, oa0, 0, 0, 0);
            oa1 = __builtin_amdgcn_mfma_f32_32x32x16_bf16(pf[ms], vf1, oa1, 0, 0, 0);
            oL  = __builtin_amdgcn_mfma_f32_32x32x16_bf16(pf[ms], onesf, oL, 0, 0, 0);
        }
        __builtin_amdgcn_s_setprio(0);

        __syncthreads();   // all waves done reading Kt/Vt
        if (mt < NN_ / 128 - 1) {
            COMMIT();
            __syncthreads();
        }
    }
    #undef ISSUE
    #undef COMMIT

    // merge m-half partials: waves 2,3 hand off via LDS (reuse Kt/Vt space)
    if (w >= 2) {
        float* red = (w == 2) ? (float*)Kt : (float*)Vt;
        #pragma unroll
        for (int reg = 0; reg < 16; reg++) {
            red[reg * 64 + lane]        = oa0[reg];
            red[1024 + reg * 64 + lane] = oa1[reg];
            red[2048 + reg * 64 + lane] = oL[reg];
        }
    }
    __syncthreads();
    if (w < 2) {
        const float* red = (w == 0) ? (const float*)Kt : (const float*)Vt;
        #pragma unroll
        for (int reg = 0; reg < 16; reg++) {
            oa0[reg] += red[reg * 64 + lane];
            oa1[reg] += red[1024 + reg * 64 + lane];
            oL[reg]  += red[2048 + reg * 64 + lane];
        }
        // epilogue: row n = (reg&3)+8*(reg>>2)+4*h5; oL has identical mapping
        #pragma unroll
        for (int reg = 0; reg < 16; reg++) {
            const int nr = (reg & 3) + 8 * (reg >> 2) + 4 * h5;
            const float il = 1.f / oL[reg];
            const size_t rowoff = base + (size_t)(n0 + nw + nr) * DIM_;
            O[rowoff + l31]      = (bf16_t)(oa0[reg] * il);
            O[rowoff + 32 + l31] = (bf16_t)(oa1[reg] * il);
        }
    }
}

// ---------------------------------------------------------------------------
extern "C" void kernel_launch(void* const* d_in, const int* in_sizes, int n_in,
                              void* d_out, int out_size, void* d_ws, size_t ws_size,
                              hipStream_t stream)
{
    const float* x  = (const float*)d_in[0];
    const float* Wq = (const float*)d_in[1];
    const float* bq = (const float*)d_in[2];
    const float* Wk = (const float*)d_in[3];
    const float* bk = (const float*)d_in[4];
    const float* Wv = (const float*)d_in[5];
    const float* bv = (const float*)d_in[6];
    const float* Wo = (const float*)d_in[7];
    const float* bo = (const float*)d_in[8];
    float* out = (float*)d_out;

    const size_t SEG = (size_t)MTOT * DIM_;   // 4M elems = 8MB bf16
    bf16_t* xb = (bf16_t*)d_ws;
    bf16_t* qb = xb + SEG;
    bf16_t* kb = qb + SEG;
    bf16_t* vb = kb + SEG;
    bf16_t* vt = xb;   // xb dead after QKV gemm
    bf16_t* ab = vb;   // vb dead after transpose

    // bf16 weights in [32MB, 40MB)
    bf16_t* wqb = vb + SEG;
    bf16_t* wkb = wqb + (size_t)DIM_ * DIM_;
    bf16_t* wvb = wkb + (size_t)DIM_ * DIM_;
    bf16_t* wob = wvb + (size_t)DIM_ * DIM_;

    cvt_bf16<<<dim3(SEG / (256 * 8)), 256, 0, stream>>>(x, xb);
    cvt_w4<<<dim3(2048), 256, 0, stream>>>(Wq, Wk, Wv, Wo, wqb, wkb, wvb, wob);

    dim3 g1(DIM_ / 128, MTOT / 128, 3);
    gemm_bb<true><<<g1, 256, 0, stream>>>(
        xb, wqb, wkb, wvb, bq, bk, bv, qb, kb, vb, EXPC_, 1.f, 1.f, MTOT, DIM_, DIM_);

    dim3 gt(NN_ / 64, BB_ * HEADS_);
    transpose_v<<<gt, 256, 0, stream>>>(vb, vt);

    attn_mfma5<<<dim3(1024), 256, 0, stream>>>(kb, qb, vt, ab);

    dim3 g3(DIM_ / 128, MTOT / 128, 1);
    gemm_bb<false><<<g3, 256, 0, stream>>>(
        ab, wob, wob, wob, bo, bo, bo, out, out, out, 1.f, 1.f, 1.f, MTOT, DIM_, DIM_);
}

// Round 8
// 181.698 us; speedup vs baseline: 1.1174x; 1.1174x over previous
//
#include <hip/hip_runtime.h>
#include <hip/hip_bf16.h>
#include <cstdint>
#include <cstddef>

typedef __bf16 bf16_t;
typedef __bf16 bf16x4 __attribute__((ext_vector_type(4)));
typedef __bf16 bf16x8 __attribute__((ext_vector_type(8)));
typedef float  f32x4  __attribute__((ext_vector_type(4)));
typedef float  f32x16 __attribute__((ext_vector_type(16)));
typedef unsigned int u32;
typedef unsigned int u32x4 __attribute__((ext_vector_type(4)));

#define DIM_   1024
#define HEADS_ 16
#define HD_    64
#define BB_    2
#define NN_    2048
#define MTOT   (BB_*NN_)
static constexpr float SCALE_ = 0.03125f;              // 1/sqrt(1024)
static constexpr float EXPC_  = 0.045084220027780106f; // SCALE * log2(e), folded into q-proj

// ---------------------------------------------------------------------------
// fp32 -> bf16 bulk converts
// ---------------------------------------------------------------------------
__global__ __launch_bounds__(256) void cvt_bf16(
    const float* __restrict__ in, bf16_t* __restrict__ out)
{
    const size_t i = ((size_t)blockIdx.x * 256 + threadIdx.x) * 8;
    f32x4 a = *(const f32x4*)(in + i);
    f32x4 b = *(const f32x4*)(in + i + 4);
    bf16x8 o;
    o[0] = (bf16_t)a.x; o[1] = (bf16_t)a.y; o[2] = (bf16_t)a.z; o[3] = (bf16_t)a.w;
    o[4] = (bf16_t)b.x; o[5] = (bf16_t)b.y; o[6] = (bf16_t)b.z; o[7] = (bf16_t)b.w;
    *(bf16x8*)(out + i) = o;
}

__global__ __launch_bounds__(256) void cvt_w4(
    const float* __restrict__ W0, const float* __restrict__ W1,
    const float* __restrict__ W2, const float* __restrict__ W3,
    bf16_t* __restrict__ o0, bf16_t* __restrict__ o1,
    bf16_t* __restrict__ o2, bf16_t* __restrict__ o3)
{
    const int bid = blockIdx.x;
    const int w   = bid >> 9;                 // 0..3
    const float* src = (w == 0) ? W0 : (w == 1) ? W1 : (w == 2) ? W2 : W3;
    bf16_t*      dst = (w == 0) ? o0 : (w == 1) ? o1 : (w == 2) ? o2 : o3;
    const size_t i = ((size_t)(bid & 511) * 256 + threadIdx.x) * 8;
    f32x4 a = *(const f32x4*)(src + i);
    f32x4 b = *(const f32x4*)(src + i + 4);
    bf16x8 o;
    o[0] = (bf16_t)a.x; o[1] = (bf16_t)a.y; o[2] = (bf16_t)a.z; o[3] = (bf16_t)a.w;
    o[4] = (bf16_t)b.x; o[5] = (bf16_t)b.y; o[6] = (bf16_t)b.z; o[7] = (bf16_t)b.w;
    *(bf16x8*)(dst + i) = o;
}

// ---------------------------------------------------------------------------
// gemm_bb: C = (A(bf16) @ Wb(bf16)^T + bias) * osc.  m97 structure.
// ---------------------------------------------------------------------------
__device__ __forceinline__ void gld16(const bf16_t* g, bf16_t* l) {
    __builtin_amdgcn_global_load_lds(
        (const __attribute__((address_space(1))) unsigned int*)g,
        (__attribute__((address_space(3))) unsigned int*)l, 16, 0, 0);
}

template<bool CBF>
__global__ __launch_bounds__(256) void gemm_bb(
    const bf16_t* __restrict__ A,
    const bf16_t* __restrict__ W0, const bf16_t* __restrict__ W1, const bf16_t* __restrict__ W2,
    const float* __restrict__ B0, const float* __restrict__ B1, const float* __restrict__ B2,
    void* __restrict__ C0, void* __restrict__ C1, void* __restrict__ C2,
    float s0, float s1, float s2,
    int M, int N, int K)
{
    const bf16_t* Wt  = (blockIdx.z == 0) ? W0 : (blockIdx.z == 1 ? W1 : W2);
    const float* bias = (blockIdx.z == 0) ? B0 : (blockIdx.z == 1 ? B1 : B2);
    void*        Cp   = (blockIdx.z == 0) ? C0 : (blockIdx.z == 1 ? C1 : C2);
    const float  osc  = (blockIdx.z == 0) ? s0 : (blockIdx.z == 1 ? s1 : s2);

    __shared__ __align__(16) bf16_t As[128 * 64];
    __shared__ __align__(16) bf16_t Bs[128 * 64];

    const int tid  = threadIdx.x;
    const int lane = tid & 63;
    const int wave = tid >> 6;
    const int wr   = wave >> 1;
    const int wc   = wave & 1;
    const int bm   = blockIdx.y, bn = blockIdx.x;

    const int l15 = lane & 15;
    const int g   = lane >> 4;

    const int grow = lane >> 3;
    const int gcol = (lane & 7) * 8;

    f32x4 acc[4][4];
    #pragma unroll
    for (int i = 0; i < 4; i++)
        #pragma unroll
        for (int j = 0; j < 4; j++)
            acc[i][j] = (f32x4){0.f, 0.f, 0.f, 0.f};

    for (int kb = 0; kb < K; kb += 64) {
        __syncthreads();
        #pragma unroll
        for (int i = 0; i < 4; i++) {
            const int r0 = i * 32 + wave * 8;
            gld16(A  + (size_t)(bm * 128 + r0 + grow) * K + kb + gcol, As + r0 * 64);
            gld16(Wt + (size_t)(bn * 128 + r0 + grow) * K + kb + gcol, Bs + r0 * 64);
        }
        __syncthreads();

        #pragma unroll
        for (int kk = 0; kk < 2; kk++) {
            bf16x8 af[4], bfr[4];
            #pragma unroll
            for (int i = 0; i < 4; i++) {
                af[i]  = *(const bf16x8*)&As[(wr * 64 + i * 16 + l15) * 64 + kk * 32 + g * 8];
                bfr[i] = *(const bf16x8*)&Bs[(wc * 64 + i * 16 + l15) * 64 + kk * 32 + g * 8];
            }
            #pragma unroll
            for (int i = 0; i < 4; i++)
                #pragma unroll
                for (int j = 0; j < 4; j++)
                    acc[i][j] = __builtin_amdgcn_mfma_f32_16x16x32_bf16(af[i], bfr[j], acc[i][j], 0, 0, 0);
        }
    }

    const int r4 = (lane >> 4) * 4;
    #pragma unroll
    for (int j = 0; j < 4; j++) {
        const int gc = bn * 128 + wc * 64 + j * 16 + l15;
        const float bv = bias[gc];
        #pragma unroll
        for (int i = 0; i < 4; i++) {
            #pragma unroll
            for (int r = 0; r < 4; r++) {
                const int gr = bm * 128 + wr * 64 + i * 16 + r4 + r;
                const float val = (acc[i][j][r] + bv) * osc;
                if (CBF) ((bf16_t*)Cp)[(size_t)gr * N + gc] = (bf16_t)val;
                else     ((float*)Cp)[(size_t)gr * N + gc]  = val;
            }
        }
    }
}

// ---------------------------------------------------------------------------
// Per-head transpose: V[b][m][h*64+d] -> Vt[(b*16+h)*64 + d][m]
// ---------------------------------------------------------------------------
__global__ __launch_bounds__(256) void transpose_v(
    const bf16_t* __restrict__ V, bf16_t* __restrict__ Vt)
{
    __shared__ __align__(16) bf16_t Ts[64 * 72];
    const int tid = threadIdx.x;
    const int mt  = blockIdx.x;
    const int bh  = blockIdx.y;
    const int b   = bh >> 4, h = bh & 15;
    const int m0  = mt * 64;
    const int r   = tid >> 2;
    const int c   = (tid & 3) * 16;

    const bf16x8* s = (const bf16x8*)(V + ((size_t)(b * NN_ + m0 + r)) * DIM_ + h * HD_ + c);
    *(bf16x8*)(Ts + r * 72 + c)     = s[0];
    *(bf16x8*)(Ts + r * 72 + c + 8) = s[1];
    __syncthreads();

    bf16x8 o0, o1;
    #pragma unroll
    for (int i = 0; i < 8; i++) o0[i] = Ts[(c + i) * 72 + r];
    #pragma unroll
    for (int i = 0; i < 8; i++) o1[i] = Ts[(c + 8 + i) * 72 + r];
    bf16_t* dst = Vt + ((size_t)bh * HD_ + r) * NN_ + m0 + c;
    *(bf16x8*)dst       = o0;
    *(bf16x8*)(dst + 8) = o1;
}

// ---------------------------------------------------------------------------
// MFMA attention v6: round-6 work decomposition (512 blocks, 128 n/block,
// wave owns 32 n, processes BOTH 64-m halves) + round-7 single-buffer LDS
// (35.8KB -> 4 blocks/CU) with issue-early/commit-late staging.
// ---------------------------------------------------------------------------
__device__ __forceinline__ u32 cvtpk_bf16(float lo, float hi) {
    u32 d;
    asm volatile("v_cvt_pk_bf16_f32 %0, %1, %2" : "=v"(d) : "v"(lo), "v"(hi));
    return d;
}

__global__ __launch_bounds__(256, 4) void attn_mfma6(
    const bf16_t* __restrict__ Qa,   // kb (attention-query rows n)
    const bf16_t* __restrict__ Ka,   // qb (attention-key rows m, pre-scaled by EXPC_)
    const bf16_t* __restrict__ Vtg,  // V^T per head [bh][d][m]
    bf16_t* __restrict__ O)
{
    __shared__ __align__(16) bf16_t Kt[128 * 72];
    __shared__ __align__(16) bf16_t Vt[64 * 136];

    const int tid  = threadIdx.x;
    const int lane = tid & 63;
    const int w    = tid >> 6;
    const int l31  = lane & 31;
    const int h5   = lane >> 5;

    // XCD-chunked swizzle: 512 blocks, 64 consecutive ids per XCD
    const int wg = blockIdx.x;
    const int id = (wg & 7) * 64 + (wg >> 3);
    const int bh = id >> 4;          // 0..31
    const int nt = id & 15;          // 0..15
    const int b  = bh >> 4, h = bh & 15;
    const int n0 = nt * 128;

    const size_t base = (size_t)b * NN_ * DIM_ + h * HD_;

    // Q-fragments (B-operand, n = n0 + w*32 + l31) straight from global
    const bf16_t* qrow = Qa + base + (size_t)(n0 + w * 32 + l31) * DIM_ + h5 * 8;
    bf16x8 qf[4];
    #pragma unroll
    for (int ks = 0; ks < 4; ks++)
        qf[ks] = *(const bf16x8*)(qrow + ks * 16);

    u32x4 onesw;
    onesw.x = 0x3F803F80u; onesw.y = 0x3F803F80u; onesw.z = 0x3F803F80u; onesw.w = 0x3F803F80u;
    const bf16x8 onesf = __builtin_bit_cast(bf16x8, onesw);

    f32x16 oa0 = {}, oa1 = {}, oL = {};

    const bf16_t* vrow   = Vtg + (size_t)bh * HD_ * NN_;
    const bf16_t* kgbase = Ka + base;
    const int kr  = tid >> 2;          // 0..63
    const int kc  = (tid & 3) * 16;    // K d-col: 0/16/32/48
    const int vcm = (tid & 3) * 32;    // V m-col base: 0/32/64/96

    bf16x8 kA0, kA1, kB0, kB1, vA0, vA1, vA2, vA3;

    #define ISSUE(m0)                                                                 \
        {                                                                             \
            const bf16x8* kp0 = (const bf16x8*)(kgbase + (size_t)((m0) + kr) * DIM_ + kc);       \
            kA0 = kp0[0]; kA1 = kp0[1];                                               \
            const bf16x8* kp1 = (const bf16x8*)(kgbase + (size_t)((m0) + 64 + kr) * DIM_ + kc);  \
            kB0 = kp1[0]; kB1 = kp1[1];                                               \
            const bf16x8* vp = (const bf16x8*)(vrow + (size_t)kr * NN_ + (m0) + vcm); \
            vA0 = vp[0]; vA1 = vp[1]; vA2 = vp[2]; vA3 = vp[3];                       \
        }
    #define COMMIT()                                                                  \
        {                                                                             \
            *(bf16x8*)(Kt + kr * 72 + kc)            = kA0;                           \
            *(bf16x8*)(Kt + kr * 72 + kc + 8)        = kA1;                           \
            *(bf16x8*)(Kt + (64 + kr) * 72 + kc)     = kB0;                           \
            *(bf16x8*)(Kt + (64 + kr) * 72 + kc + 8) = kB1;                           \
            bf16_t* vd = Vt + kr * 136 + vcm;                                         \
            *(bf16x8*)(vd)      = vA0; *(bf16x8*)(vd + 8)  = vA1;                     \
            *(bf16x8*)(vd + 16) = vA2; *(bf16x8*)(vd + 24) = vA3;                     \
        }

    ISSUE(0);
    COMMIT();
    __syncthreads();

    for (int mt = 0; mt < NN_ / 128; mt++) {
        if (mt < NN_ / 128 - 1) ISSUE((mt + 1) * 128);

        #pragma unroll
        for (int half = 0; half < 2; half++) {
            const int mo = half * 64;

            // S^T: lane holds 32 P-vals for n = w*32 + l31
            f32x16 sa0 = {}, sa1 = {};
            __builtin_amdgcn_s_setprio(1);
            #pragma unroll
            for (int ks = 0; ks < 4; ks++) {
                bf16x8 kf0 = *(const bf16x8*)&Kt[(mo + l31) * 72 + ks * 16 + h5 * 8];
                bf16x8 kf1 = *(const bf16x8*)&Kt[(mo + 32 + l31) * 72 + ks * 16 + h5 * 8];
                sa0 = __builtin_amdgcn_mfma_f32_32x32x16_bf16(kf0, qf[ks], sa0, 0, 0, 0);
                sa1 = __builtin_amdgcn_mfma_f32_32x32x16_bf16(kf1, qf[ks], sa1, 0, 0, 0);
            }
            __builtin_amdgcn_s_setprio(0);

            // P = exp2(S^T)  (scale pre-folded into Ka)
            float p0[16], p1[16];
            #pragma unroll
            for (int r = 0; r < 16; r++) { p0[r] = exp2f(sa0[r]); p1[r] = exp2f(sa1[r]); }

            // PV A-fragments in-register: 16 cvt_pk + 8 permlane32_swap
            bf16x8 pf[4];
            #pragma unroll
            for (int mb = 0; mb < 4; mb++) {
                const float* pp = (mb & 2) ? p1 : p0;
                const int rb = (mb & 1) * 8;
                u32 x0 = cvtpk_bf16(pp[rb + 0], pp[rb + 1]);
                u32 x1 = cvtpk_bf16(pp[rb + 2], pp[rb + 3]);
                u32 y0 = cvtpk_bf16(pp[rb + 4], pp[rb + 5]);
                u32 y1 = cvtpk_bf16(pp[rb + 6], pp[rb + 7]);
                asm volatile("v_permlane32_swap_b32 %0, %1" : "+v"(x0), "+v"(y0));
                asm volatile("v_permlane32_swap_b32 %0, %1" : "+v"(x1), "+v"(y1));
                u32x4 t; t.x = x0; t.y = x1; t.z = y0; t.w = y1;
                pf[mb] = __builtin_bit_cast(bf16x8, t);
            }

            // O += P·V ; L += P·1
            __builtin_amdgcn_s_setprio(1);
            #pragma unroll
            for (int ms = 0; ms < 4; ms++) {
                bf16x8 vf0 = *(const bf16x8*)&Vt[l31 * 136 + mo + ms * 16 + h5 * 8];
                bf16x8 vf1 = *(const bf16x8*)&Vt[(32 + l31) * 136 + mo + ms * 16 + h5 * 8];
                oa0 = __builtin_amdgcn_mfma_f32_32x32x16_bf16(pf[ms], vf0, oa0, 0, 0, 0);
                oa1 = __builtin_amdgcn_mfma_f32_32x32x16_bf16(pf[ms], vf1, oa1, 0, 0, 0);
                oL  = __builtin_amdgcn_mfma_f32_32x32x16_bf16(pf[ms], onesf, oL, 0, 0, 0);
            }
            __builtin_amdgcn_s_setprio(0);
        }

        __syncthreads();   // all waves done reading Kt/Vt
        if (mt < NN_ / 128 - 1) {
            COMMIT();
            __syncthreads();
        }
    }
    #undef ISSUE
    #undef COMMIT

    // epilogue: row n = (reg&3)+8*(reg>>2)+4*h5; oL has identical reg mapping
    #pragma unroll
    for (int reg = 0; reg < 16; reg++) {
        const int nr = (reg & 3) + 8 * (reg >> 2) + 4 * h5;
        const float il = 1.f / oL[reg];
        const size_t rowoff = base + (size_t)(n0 + w * 32 + nr) * DIM_;
        O[rowoff + l31]      = (bf16_t)(oa0[reg] * il);
        O[rowoff + 32 + l31] = (bf16_t)(oa1[reg] * il);
    }
}

// ---------------------------------------------------------------------------
extern "C" void kernel_launch(void* const* d_in, const int* in_sizes, int n_in,
                              void* d_out, int out_size, void* d_ws, size_t ws_size,
                              hipStream_t stream)
{
    const float* x  = (const float*)d_in[0];
    const float* Wq = (const float*)d_in[1];
    const float* bq = (const float*)d_in[2];
    const float* Wk = (const float*)d_in[3];
    const float* bk = (const float*)d_in[4];
    const float* Wv = (const float*)d_in[5];
    const float* bv = (const float*)d_in[6];
    const float* Wo = (const float*)d_in[7];
    const float* bo = (const float*)d_in[8];
    float* out = (float*)d_out;

    const size_t SEG = (size_t)MTOT * DIM_;   // 4M elems = 8MB bf16
    bf16_t* xb = (bf16_t*)d_ws;
    bf16_t* qb = xb + SEG;
    bf16_t* kb = qb + SEG;
    bf16_t* vb = kb + SEG;
    bf16_t* vt = xb;   // xb dead after QKV gemm
    bf16_t* ab = vb;   // vb dead after transpose

    // bf16 weights in [32MB, 40MB)
    bf16_t* wqb = vb + SEG;
    bf16_t* wkb = wqb + (size_t)DIM_ * DIM_;
    bf16_t* wvb = wkb + (size_t)DIM_ * DIM_;
    bf16_t* wob = wvb + (size_t)DIM_ * DIM_;

    cvt_bf16<<<dim3(SEG / (256 * 8)), 256, 0, stream>>>(x, xb);
    cvt_w4<<<dim3(2048), 256, 0, stream>>>(Wq, Wk, Wv, Wo, wqb, wkb, wvb, wob);

    dim3 g1(DIM_ / 128, MTOT / 128, 3);
    gemm_bb<true><<<g1, 256, 0, stream>>>(
        xb, wqb, wkb, wvb, bq, bk, bv, qb, kb, vb, EXPC_, 1.f, 1.f, MTOT, DIM_, DIM_);

    dim3 gt(NN_ / 64, BB_ * HEADS_);
    transpose_v<<<gt, 256, 0, stream>>>(vb, vt);

    attn_mfma6<<<dim3(512), 256, 0, stream>>>(kb, qb, vt, ab);

    dim3 g3(DIM_ / 128, MTOT / 128, 1);
    gemm_bb<false><<<g3, 256, 0, stream>>>(
        ab, wob, wob, wob, bo, bo, bo, out, out, out, 1.f, 1.f, 1.f, MTOT, DIM_, DIM_);
}

// Round 9
// 157.581 us; speedup vs baseline: 1.2884x; 1.1530x over previous
//
#include <hip/hip_runtime.h>
#include <hip/hip_bf16.h>
#include <cstdint>
#include <cstddef>

typedef __bf16 bf16_t;
typedef __bf16 bf16x4 __attribute__((ext_vector_type(4)));
typedef __bf16 bf16x8 __attribute__((ext_vector_type(8)));
typedef float  f32x4  __attribute__((ext_vector_type(4)));
typedef float  f32x16 __attribute__((ext_vector_type(16)));
typedef unsigned int u32;
typedef unsigned int u32x4 __attribute__((ext_vector_type(4)));

#define DIM_   1024
#define HEADS_ 16
#define HD_    64
#define BB_    2
#define NN_    2048
#define MTOT   (BB_*NN_)
static constexpr float SCALE_ = 0.03125f;              // 1/sqrt(1024)
static constexpr float EXPC_  = 0.045084220027780106f; // SCALE * log2(e), folded into q-proj

// ---------------------------------------------------------------------------
// fp32 -> bf16 bulk converts
// ---------------------------------------------------------------------------
__global__ __launch_bounds__(256) void cvt_bf16(
    const float* __restrict__ in, bf16_t* __restrict__ out)
{
    const size_t i = ((size_t)blockIdx.x * 256 + threadIdx.x) * 8;
    f32x4 a = *(const f32x4*)(in + i);
    f32x4 b = *(const f32x4*)(in + i + 4);
    bf16x8 o;
    o[0] = (bf16_t)a.x; o[1] = (bf16_t)a.y; o[2] = (bf16_t)a.z; o[3] = (bf16_t)a.w;
    o[4] = (bf16_t)b.x; o[5] = (bf16_t)b.y; o[6] = (bf16_t)b.z; o[7] = (bf16_t)b.w;
    *(bf16x8*)(out + i) = o;
}

__global__ __launch_bounds__(256) void cvt_w4(
    const float* __restrict__ W0, const float* __restrict__ W1,
    const float* __restrict__ W2, const float* __restrict__ W3,
    bf16_t* __restrict__ o0, bf16_t* __restrict__ o1,
    bf16_t* __restrict__ o2, bf16_t* __restrict__ o3)
{
    const int bid = blockIdx.x;
    const int w   = bid >> 9;                 // 0..3
    const float* src = (w == 0) ? W0 : (w == 1) ? W1 : (w == 2) ? W2 : W3;
    bf16_t*      dst = (w == 0) ? o0 : (w == 1) ? o1 : (w == 2) ? o2 : o3;
    const size_t i = ((size_t)(bid & 511) * 256 + threadIdx.x) * 8;
    f32x4 a = *(const f32x4*)(src + i);
    f32x4 b = *(const f32x4*)(src + i + 4);
    bf16x8 o;
    o[0] = (bf16_t)a.x; o[1] = (bf16_t)a.y; o[2] = (bf16_t)a.z; o[3] = (bf16_t)a.w;
    o[4] = (bf16_t)b.x; o[5] = (bf16_t)b.y; o[6] = (bf16_t)b.z; o[7] = (bf16_t)b.w;
    *(bf16x8*)(dst + i) = o;
}

// ---------------------------------------------------------------------------
// gemm_bb: C = (A(bf16) @ Wb(bf16)^T + bias) * osc.  m97 structure.
// ---------------------------------------------------------------------------
__device__ __forceinline__ void gld16(const bf16_t* g, bf16_t* l) {
    __builtin_amdgcn_global_load_lds(
        (const __attribute__((address_space(1))) unsigned int*)g,
        (__attribute__((address_space(3))) unsigned int*)l, 16, 0, 0);
}

template<bool CBF>
__global__ __launch_bounds__(256) void gemm_bb(
    const bf16_t* __restrict__ A,
    const bf16_t* __restrict__ W0, const bf16_t* __restrict__ W1, const bf16_t* __restrict__ W2,
    const float* __restrict__ B0, const float* __restrict__ B1, const float* __restrict__ B2,
    void* __restrict__ C0, void* __restrict__ C1, void* __restrict__ C2,
    float s0, float s1, float s2,
    int M, int N, int K)
{
    const bf16_t* Wt  = (blockIdx.z == 0) ? W0 : (blockIdx.z == 1 ? W1 : W2);
    const float* bias = (blockIdx.z == 0) ? B0 : (blockIdx.z == 1 ? B1 : B2);
    void*        Cp   = (blockIdx.z == 0) ? C0 : (blockIdx.z == 1 ? C1 : C2);
    const float  osc  = (blockIdx.z == 0) ? s0 : (blockIdx.z == 1 ? s1 : s2);

    __shared__ __align__(16) bf16_t As[128 * 64];
    __shared__ __align__(16) bf16_t Bs[128 * 64];

    const int tid  = threadIdx.x;
    const int lane = tid & 63;
    const int wave = tid >> 6;
    const int wr   = wave >> 1;
    const int wc   = wave & 1;
    const int bm   = blockIdx.y, bn = blockIdx.x;

    const int l15 = lane & 15;
    const int g   = lane >> 4;

    const int grow = lane >> 3;
    const int gcol = (lane & 7) * 8;

    f32x4 acc[4][4];
    #pragma unroll
    for (int i = 0; i < 4; i++)
        #pragma unroll
        for (int j = 0; j < 4; j++)
            acc[i][j] = (f32x4){0.f, 0.f, 0.f, 0.f};

    for (int kb = 0; kb < K; kb += 64) {
        __syncthreads();
        #pragma unroll
        for (int i = 0; i < 4; i++) {
            const int r0 = i * 32 + wave * 8;
            gld16(A  + (size_t)(bm * 128 + r0 + grow) * K + kb + gcol, As + r0 * 64);
            gld16(Wt + (size_t)(bn * 128 + r0 + grow) * K + kb + gcol, Bs + r0 * 64);
        }
        __syncthreads();

        #pragma unroll
        for (int kk = 0; kk < 2; kk++) {
            bf16x8 af[4], bfr[4];
            #pragma unroll
            for (int i = 0; i < 4; i++) {
                af[i]  = *(const bf16x8*)&As[(wr * 64 + i * 16 + l15) * 64 + kk * 32 + g * 8];
                bfr[i] = *(const bf16x8*)&Bs[(wc * 64 + i * 16 + l15) * 64 + kk * 32 + g * 8];
            }
            #pragma unroll
            for (int i = 0; i < 4; i++)
                #pragma unroll
                for (int j = 0; j < 4; j++)
                    acc[i][j] = __builtin_amdgcn_mfma_f32_16x16x32_bf16(af[i], bfr[j], acc[i][j], 0, 0, 0);
        }
    }

    const int r4 = (lane >> 4) * 4;
    #pragma unroll
    for (int j = 0; j < 4; j++) {
        const int gc = bn * 128 + wc * 64 + j * 16 + l15;
        const float bv = bias[gc];
        #pragma unroll
        for (int i = 0; i < 4; i++) {
            #pragma unroll
            for (int r = 0; r < 4; r++) {
                const int gr = bm * 128 + wr * 64 + i * 16 + r4 + r;
                const float val = (acc[i][j][r] + bv) * osc;
                if (CBF) ((bf16_t*)Cp)[(size_t)gr * N + gc] = (bf16_t)val;
                else     ((float*)Cp)[(size_t)gr * N + gc]  = val;
            }
        }
    }
}

// ---------------------------------------------------------------------------
// Per-head transpose: V[b][m][h*64+d] -> Vt[(b*16+h)*64 + d][m]
// ---------------------------------------------------------------------------
__global__ __launch_bounds__(256) void transpose_v(
    const bf16_t* __restrict__ V, bf16_t* __restrict__ Vt)
{
    __shared__ __align__(16) bf16_t Ts[64 * 72];
    const int tid = threadIdx.x;
    const int mt  = blockIdx.x;
    const int bh  = blockIdx.y;
    const int b   = bh >> 4, h = bh & 15;
    const int m0  = mt * 64;
    const int r   = tid >> 2;
    const int c   = (tid & 3) * 16;

    const bf16x8* s = (const bf16x8*)(V + ((size_t)(b * NN_ + m0 + r)) * DIM_ + h * HD_ + c);
    *(bf16x8*)(Ts + r * 72 + c)     = s[0];
    *(bf16x8*)(Ts + r * 72 + c + 8) = s[1];
    __syncthreads();

    bf16x8 o0, o1;
    #pragma unroll
    for (int i = 0; i < 8; i++) o0[i] = Ts[(c + i) * 72 + r];
    #pragma unroll
    for (int i = 0; i < 8; i++) o1[i] = Ts[(c + 8 + i) * 72 + r];
    bf16_t* dst = Vt + ((size_t)bh * HD_ + r) * NN_ + m0 + c;
    *(bf16x8*)dst       = o0;
    *(bf16x8*)(dst + 8) = o1;
}

// ---------------------------------------------------------------------------
// MFMA attention v7: 512 blocks x 512 threads (8 waves).
// Waves 0-3: n-strips (w&3)*32, m-half 0.  Waves 4-7: same n, m-half 1.
// Double-buffered K/V, 1 barrier/tile. O/L partials merged via LDS at end.
// Same per-block fetch as round 6; 16 waves/CU (2 blocks x 8 waves).
// ---------------------------------------------------------------------------
__device__ __forceinline__ u32 cvtpk_bf16(float lo, float hi) {
    u32 d;
    asm volatile("v_cvt_pk_bf16_f32 %0, %1, %2" : "=v"(d) : "v"(lo), "v"(hi));
    return d;
}

__global__ __launch_bounds__(512, 4) void attn_mfma7(
    const bf16_t* __restrict__ Qa,   // kb (attention-query rows n)
    const bf16_t* __restrict__ Ka,   // qb (attention-key rows m, pre-scaled by EXPC_)
    const bf16_t* __restrict__ Vtg,  // V^T per head [bh][d][m]
    bf16_t* __restrict__ O)
{
    __shared__ __align__(16) bf16_t Kt[2][128 * 72];   // 36.9 KB
    __shared__ __align__(16) bf16_t Vt[2][64 * 136];   // 34.8 KB

    const int tid  = threadIdx.x;
    const int lane = tid & 63;
    const int w    = tid >> 6;       // 0..7
    const int l31  = lane & 31;
    const int h5   = lane >> 5;

    const int nw = (w & 3) * 32;     // wave's n-offset in block
    const int mo = (w >> 2) * 64;    // wave's m-half within each 128-m tile

    // XCD-chunked swizzle: 512 blocks, 64 consecutive ids per XCD
    const int wg = blockIdx.x;
    const int id = (wg & 7) * 64 + (wg >> 3);
    const int bh = id >> 4;          // 0..31
    const int nt = id & 15;          // 0..15
    const int b  = bh >> 4, h = bh & 15;
    const int n0 = nt * 128;

    const size_t base = (size_t)b * NN_ * DIM_ + h * HD_;

    // Q-fragments (B-operand, n = n0 + nw + l31) straight from global
    const bf16_t* qrow = Qa + base + (size_t)(n0 + nw + l31) * DIM_ + h5 * 8;
    bf16x8 qf[4];
    #pragma unroll
    for (int ks = 0; ks < 4; ks++)
        qf[ks] = *(const bf16x8*)(qrow + ks * 16);

    u32x4 onesw;
    onesw.x = 0x3F803F80u; onesw.y = 0x3F803F80u; onesw.z = 0x3F803F80u; onesw.w = 0x3F803F80u;
    const bf16x8 onesf = __builtin_bit_cast(bf16x8, onesw);

    f32x16 oa0 = {}, oa1 = {}, oL = {};

    const bf16_t* vrow   = Vtg + (size_t)bh * HD_ * NN_;
    const bf16_t* kgbase = Ka + base;

    // staging (512 threads): K 128x64 (2 rows/thread of 8), V^T 64x128 (1 row, 16 m)
    const int kr2 = tid >> 3;          // 0..63
    const int kc2 = (tid & 7) * 8;     // K d-col: 0..56
    const int vc2 = (tid & 7) * 16;    // V m-col: 0..112

    bf16x8 kA0, kB0, vA0, vA1;

    #define ISSUE(m0)                                                                        \
        {                                                                                    \
            kA0 = *(const bf16x8*)(kgbase + (size_t)((m0) + kr2) * DIM_ + kc2);              \
            kB0 = *(const bf16x8*)(kgbase + (size_t)((m0) + 64 + kr2) * DIM_ + kc2);         \
            const bf16x8* vp = (const bf16x8*)(vrow + (size_t)kr2 * NN_ + (m0) + vc2);       \
            vA0 = vp[0]; vA1 = vp[1];                                                        \
        }
    #define COMMIT(buf)                                                                      \
        {                                                                                    \
            *(bf16x8*)(Kt[buf] + kr2 * 72 + kc2)        = kA0;                               \
            *(bf16x8*)(Kt[buf] + (64 + kr2) * 72 + kc2) = kB0;                               \
            bf16_t* vd = Vt[buf] + kr2 * 136 + vc2;                                          \
            *(bf16x8*)(vd)     = vA0;                                                        \
            *(bf16x8*)(vd + 8) = vA1;                                                        \
        }

    ISSUE(0);
    COMMIT(0);
    __syncthreads();

    for (int mt = 0; mt < NN_ / 128; mt++) {
        const int cur = mt & 1;
        if (mt < NN_ / 128 - 1) ISSUE((mt + 1) * 128);

        const bf16_t* KtC = Kt[cur];
        const bf16_t* VtC = Vt[cur];

        // S^T for this wave's m-half: lane holds 32 P-vals for n = nw + l31
        f32x16 sa0 = {}, sa1 = {};
        __builtin_amdgcn_s_setprio(1);
        #pragma unroll
        for (int ks = 0; ks < 4; ks++) {
            bf16x8 kf0 = *(const bf16x8*)&KtC[(mo + l31) * 72 + ks * 16 + h5 * 8];
            bf16x8 kf1 = *(const bf16x8*)&KtC[(mo + 32 + l31) * 72 + ks * 16 + h5 * 8];
            sa0 = __builtin_amdgcn_mfma_f32_32x32x16_bf16(kf0, qf[ks], sa0, 0, 0, 0);
            sa1 = __builtin_amdgcn_mfma_f32_32x32x16_bf16(kf1, qf[ks], sa1, 0, 0, 0);
        }
        __builtin_amdgcn_s_setprio(0);

        // P = exp2(S^T)  (scale pre-folded into Ka)
        float p0[16], p1[16];
        #pragma unroll
        for (int r = 0; r < 16; r++) { p0[r] = exp2f(sa0[r]); p1[r] = exp2f(sa1[r]); }

        // PV A-fragments in-register: 16 cvt_pk + 8 permlane32_swap
        bf16x8 pf[4];
        #pragma unroll
        for (int mb = 0; mb < 4; mb++) {
            const float* pp = (mb & 2) ? p1 : p0;
            const int rb = (mb & 1) * 8;
            u32 x0 = cvtpk_bf16(pp[rb + 0], pp[rb + 1]);
            u32 x1 = cvtpk_bf16(pp[rb + 2], pp[rb + 3]);
            u32 y0 = cvtpk_bf16(pp[rb + 4], pp[rb + 5]);
            u32 y1 = cvtpk_bf16(pp[rb + 6], pp[rb + 7]);
            asm volatile("v_permlane32_swap_b32 %0, %1" : "+v"(x0), "+v"(y0));
            asm volatile("v_permlane32_swap_b32 %0, %1" : "+v"(x1), "+v"(y1));
            u32x4 t; t.x = x0; t.y = x1; t.z = y0; t.w = y1;
            pf[mb] = __builtin_bit_cast(bf16x8, t);
        }

        // O += P·V ; L += P·1   (this wave's m-half)
        __builtin_amdgcn_s_setprio(1);
        #pragma unroll
        for (int ms = 0; ms < 4; ms++) {
            bf16x8 vf0 = *(const bf16x8*)&VtC[l31 * 136 + mo + ms * 16 + h5 * 8];
            bf16x8 vf1 = *(const bf16x8*)&VtC[(32 + l31) * 136 + mo + ms * 16 + h5 * 8];
            oa0 = __builtin_amdgcn_mfma_f32_32x32x16_bf16(pf[ms], vf0, oa0, 0, 0, 0);
            oa1 = __builtin_amdgcn_mfma_f32_32x32x16_bf16(pf[ms], vf1, oa1, 0, 0, 0);
            oL  = __builtin_amdgcn_mfma_f32_32x32x16_bf16(pf[ms], onesf, oL, 0, 0, 0);
        }
        __builtin_amdgcn_s_setprio(0);

        if (mt < NN_ / 128 - 1) COMMIT(cur ^ 1);
        __syncthreads();
    }
    #undef ISSUE
    #undef COMMIT

    // merge m-half partials: waves 4-7 write 48 f32/lane, waves 0-3 add.
    // slots: w=4,5 -> Kt (2 x 12KB <= 36.9KB); w=6,7 -> Vt (2 x 12KB <= 34.8KB)
    if (w >= 4) {
        float* buf = (w < 6) ? ((float*)Kt + (w - 4) * 3072)
                             : ((float*)Vt + (w - 6) * 3072);
        #pragma unroll
        for (int reg = 0; reg < 16; reg++) {
            buf[reg * 64 + lane]        = oa0[reg];
            buf[1024 + reg * 64 + lane] = oa1[reg];
            buf[2048 + reg * 64 + lane] = oL[reg];
        }
    }
    __syncthreads();
    if (w < 4) {
        const float* buf = (w < 2) ? ((const float*)Kt + w * 3072)
                                   : ((const float*)Vt + (w - 2) * 3072);
        #pragma unroll
        for (int reg = 0; reg < 16; reg++) {
            oa0[reg] += buf[reg * 64 + lane];
            oa1[reg] += buf[1024 + reg * 64 + lane];
            oL[reg]  += buf[2048 + reg * 64 + lane];
        }
        // epilogue: row n = (reg&3)+8*(reg>>2)+4*h5; oL has identical mapping
        #pragma unroll
        for (int reg = 0; reg < 16; reg++) {
            const int nr = (reg & 3) + 8 * (reg >> 2) + 4 * h5;
            const float il = 1.f / oL[reg];
            const size_t rowoff = base + (size_t)(n0 + nw + nr) * DIM_;
            O[rowoff + l31]      = (bf16_t)(oa0[reg] * il);
            O[rowoff + 32 + l31] = (bf16_t)(oa1[reg] * il);
        }
    }
}

// ---------------------------------------------------------------------------
extern "C" void kernel_launch(void* const* d_in, const int* in_sizes, int n_in,
                              void* d_out, int out_size, void* d_ws, size_t ws_size,
                              hipStream_t stream)
{
    const float* x  = (const float*)d_in[0];
    const float* Wq = (const float*)d_in[1];
    const float* bq = (const float*)d_in[2];
    const float* Wk = (const float*)d_in[3];
    const float* bk = (const float*)d_in[4];
    const float* Wv = (const float*)d_in[5];
    const float* bv = (const float*)d_in[6];
    const float* Wo = (const float*)d_in[7];
    const float* bo = (const float*)d_in[8];
    float* out = (float*)d_out;

    const size_t SEG = (size_t)MTOT * DIM_;   // 4M elems = 8MB bf16
    bf16_t* xb = (bf16_t*)d_ws;
    bf16_t* qb = xb + SEG;
    bf16_t* kb = qb + SEG;
    bf16_t* vb = kb + SEG;
    bf16_t* vt = xb;   // xb dead after QKV gemm
    bf16_t* ab = vb;   // vb dead after transpose

    // bf16 weights in [32MB, 40MB)
    bf16_t* wqb = vb + SEG;
    bf16_t* wkb = wqb + (size_t)DIM_ * DIM_;
    bf16_t* wvb = wkb + (size_t)DIM_ * DIM_;
    bf16_t* wob = wvb + (size_t)DIM_ * DIM_;

    cvt_bf16<<<dim3(SEG / (256 * 8)), 256, 0, stream>>>(x, xb);
    cvt_w4<<<dim3(2048), 256, 0, stream>>>(Wq, Wk, Wv, Wo, wqb, wkb, wvb, wob);

    dim3 g1(DIM_ / 128, MTOT / 128, 3);
    gemm_bb<true><<<g1, 256, 0, stream>>>(
        xb, wqb, wkb, wvb, bq, bk, bv, qb, kb, vb, EXPC_, 1.f, 1.f, MTOT, DIM_, DIM_);

    dim3 gt(NN_ / 64, BB_ * HEADS_);
    transpose_v<<<gt, 256, 0, stream>>>(vb, vt);

    attn_mfma7<<<dim3(512), 512, 0, stream>>>(kb, qb, vt, ab);

    dim3 g3(DIM_ / 128, MTOT / 128, 1);
    gemm_bb<false><<<g3, 256, 0, stream>>>(
        ab, wob, wob, wob, bo, bo, bo, out, out, out, 1.f, 1.f, 1.f, MTOT, DIM_, DIM_);
}